// Round 1
// 3025.148 us; speedup vs baseline: 2.9090x; 2.9090x over previous
//
#include <hip/hip_runtime.h>
#include <stdint.h>
#include <type_traits>

typedef unsigned short u16;
typedef __attribute__((ext_vector_type(8))) short short8_t;
typedef __attribute__((ext_vector_type(8))) __bf16 bf16x8_t;
typedef __attribute__((ext_vector_type(4))) float f32x4;

// ROCm builds differ on the gfx950 bf16 MFMA builtin operand type
// (v8i16 vs v8bf16). Probe at compile time; bits are identical either way.
template <class T, class = void>
struct mfma_takes : std::false_type {};
template <class T>
struct mfma_takes<T, std::void_t<decltype(__builtin_amdgcn_mfma_f32_16x16x32_bf16(
                         std::declval<T>(), std::declval<T>(), std::declval<f32x4>(), 0, 0, 0))>>
    : std::true_type {};
using frag_t = std::conditional_t<mfma_takes<short8_t>::value, short8_t, bf16x8_t>;

__device__ __forceinline__ u16 bf16_rne(float f) {
    uint32_t u = __builtin_bit_cast(uint32_t, f);
    return (u16)((u + 0x7fffu + ((u >> 16) & 1u)) >> 16);
}
__device__ __forceinline__ float bf16_hi_f(u16 h) {
    return __builtin_bit_cast(float, (uint32_t)h << 16);
}

// ---------- transpose + split fp32 W[K][Nfull] cols [c0,c0+Ncols) -> bf16 hi/lo [Ncols][K]
__global__ __launch_bounds__(256) void transpose_split(const float* __restrict__ W,
                                                       u16* __restrict__ Th,
                                                       u16* __restrict__ Tl,
                                                       int K, int Nfull, int c0, int Ncols) {
    __shared__ float tile[32][33];
    const int nb = Ncols >> 5;
    const int bk = blockIdx.x / nb;
    const int bn = blockIdx.x % nb;
    const int tx = threadIdx.x & 31;
    const int ty = threadIdx.x >> 5;
#pragma unroll
    for (int i = 0; i < 4; i++) {
        int r = (i << 3) + ty;
        tile[r][tx] = W[(size_t)((bk << 5) + r) * Nfull + c0 + (bn << 5) + tx];
    }
    __syncthreads();
#pragma unroll
    for (int i = 0; i < 4; i++) {
        int r = (i << 3) + ty;
        float v = tile[tx][r];
        u16 h = bf16_rne(v);
        u16 l = bf16_rne(v - bf16_hi_f(h));
        size_t o = (size_t)((bn << 5) + r) * K + (bk << 5) + tx;
        Th[o] = h;
        Tl[o] = l;
    }
}

// ---------- split-bf16 MFMA GEMM: C[M][Nfull] cols [n0,n0+Nloc) = A[M][K] @ B
// A fp32 row-major (split to hi/lo in-register during staging).
// B given pre-split+transposed: BTh/BTl bf16 [Nloc][K] row-major.
// 128x128 tile, BK=32, 4 waves of 64x64, v_mfma_f32_16x16x32_bf16,
// 3 MFMAs per fragment pair (hi*hi + lo*hi + hi*lo) ~ fp32 accuracy.
// LDS rows padded to 40 bf16 (80B): 16-row frag reads spread all 32 banks.
__global__ __launch_bounds__(256) void gemm_split_bf16(const float* __restrict__ A,
                                                       const u16* __restrict__ BTh,
                                                       const u16* __restrict__ BTl,
                                                       float* __restrict__ C,
                                                       int M, int K, int Nfull, int n0, int Nloc) {
    __shared__ alignas(16) u16 Ah[128][40];
    __shared__ alignas(16) u16 Al[128][40];
    __shared__ alignas(16) u16 Bh[128][40];
    __shared__ alignas(16) u16 Bl[128][40];

    const int t = threadIdx.x;
    const int nb = Nloc >> 7;
    const int bm = blockIdx.x / nb;
    const int bn = blockIdx.x % nb;
    const int m0 = bm << 7;
    const int nl0 = bn << 7;

    const int lane = t & 63;
    const int wid = t >> 6;
    const int wm = (wid >> 1) << 6;  // wave row offset in 128x128 tile
    const int wn = (wid & 1) << 6;   // wave col offset
    const int fr = lane & 15;        // frag row (A) / col (B,C)
    const int fk = (lane >> 4) << 3; // frag k offset (8 contiguous bf16)

    const int sr = t >> 3;        // staging row 0..31
    const int sc = (t & 7) << 2;  // staging col 0..28 step 4

    f32x4 acc[4][4];
#pragma unroll
    for (int m = 0; m < 4; m++)
#pragma unroll
        for (int n = 0; n < 4; n++) acc[m][n] = (f32x4)(0.0f);

    const int ksteps = K >> 5;
    for (int kt = 0; kt < ksteps; kt++) {
        const int k0 = kt << 5;
        if (kt) __syncthreads();  // prior iter frag reads done before overwrite
        // stage A tile (fp32 -> hi/lo bf16), rows 128 x 32 k
#pragma unroll
        for (int rg = 0; rg < 4; rg++) {
            int row = (rg << 5) + sr;
            float4 v = *(const float4*)(A + (size_t)(m0 + row) * K + k0 + sc);
            u16 hx = bf16_rne(v.x), hy = bf16_rne(v.y), hz = bf16_rne(v.z), hw = bf16_rne(v.w);
            *(ushort4*)&Ah[row][sc] = make_ushort4(hx, hy, hz, hw);
            *(ushort4*)&Al[row][sc] =
                make_ushort4(bf16_rne(v.x - bf16_hi_f(hx)), bf16_rne(v.y - bf16_hi_f(hy)),
                             bf16_rne(v.z - bf16_hi_f(hz)), bf16_rne(v.w - bf16_hi_f(hw)));
        }
        // stage B tile (pre-split bf16), 128 n-rows x 32 k
#pragma unroll
        for (int rg = 0; rg < 4; rg++) {
            int row = (rg << 5) + sr;
            size_t o = (size_t)(nl0 + row) * K + k0 + sc;
            *(ushort4*)&Bh[row][sc] = *(const ushort4*)(BTh + o);
            *(ushort4*)&Bl[row][sc] = *(const ushort4*)(BTl + o);
        }
        __syncthreads();

        frag_t ah[4], al[4], bh[4], bl[4];
#pragma unroll
        for (int i = 0; i < 4; i++) {
            int r = (i << 4) + fr;
            ah[i] = *(const frag_t*)&Ah[wm + r][fk];
            al[i] = *(const frag_t*)&Al[wm + r][fk];
            bh[i] = *(const frag_t*)&Bh[wn + r][fk];
            bl[i] = *(const frag_t*)&Bl[wn + r][fk];
        }
#pragma unroll
        for (int m = 0; m < 4; m++)
#pragma unroll
            for (int n = 0; n < 4; n++) {
                acc[m][n] = __builtin_amdgcn_mfma_f32_16x16x32_bf16(ah[m], bh[n], acc[m][n], 0, 0, 0);
                acc[m][n] = __builtin_amdgcn_mfma_f32_16x16x32_bf16(al[m], bh[n], acc[m][n], 0, 0, 0);
                acc[m][n] = __builtin_amdgcn_mfma_f32_16x16x32_bf16(ah[m], bl[n], acc[m][n], 0, 0, 0);
            }
    }

    // epilogue: C/D layout col=lane&15, row=(lane>>4)*4+reg (m89-verified)
#pragma unroll
    for (int m = 0; m < 4; m++) {
        int r0 = m0 + wm + (m << 4) + ((lane >> 4) << 2);
#pragma unroll
        for (int n = 0; n < 4; n++) {
            int cc = n0 + nl0 + wn + (n << 4) + fr;
#pragma unroll
            for (int r = 0; r < 4; r++)
                C[(size_t)(r0 + r) * Nfull + cc] = acc[m][n][r];
        }
    }
}

// ---------- RoPE fp32 in-place on q,k halves of qkv [4096][6144] (unchanged) ----------
__global__ __launch_bounds__(256) void rope_f32_v8(float* __restrict__ qkv,
                                                   const float* __restrict__ freqs) {
    int idx = blockIdx.x * 256 + threadIdx.x;  // 4096*2048 (row, pair)
    int row = idx >> 11;
    int p = idx & 2047;
    int part = p >> 10;  // 0=q, 1=k
    int rem = p & 1023;
    int h = rem >> 6;  // head (64 pairs per head)
    int d2 = rem & 63;
    int s = row & 2047;  // row = b*2048 + s
    size_t base = (size_t)row * 6144 + part * 2048 + h * 128 + 2 * d2;
    float c = freqs[(s * 64 + d2) * 2 + 0];
    float sn = freqs[(s * 64 + d2) * 2 + 1];
    float x0 = qkv[base];
    float x1 = qkv[base + 1];
    qkv[base] = x0 * c - x1 * sn;
    qkv[base + 1] = x1 * c + x0 * sn;
}

// ---------- causal flash attention, fp32 (unchanged this round) ----------
__global__ __launch_bounds__(256) void attn_f32_v8(const float* __restrict__ qkv,
                                                   float* __restrict__ out) {
    __shared__ float Ks[32][132];
    __shared__ float Vs[32][132];
    int t = threadIdx.x;
    int row_l = t >> 2;  // 0..63
    int dseg = t & 3;    // 0..3
    int bx = blockIdx.x;
    int qb = bx & 31;
    int h = (bx >> 5) & 15;
    int b = bx >> 9;
    int q = qb * 64 + row_l;
    const float scale = 0.08838834764831845f;  // 1/sqrt(128)
    size_t rowbase = (size_t)(b * 2048 + q) * 6144 + h * 128 + dseg * 32;

    float qv[32];
    for (int i = 0; i < 32; i++) qv[i] = qkv[rowbase + i];

    float m = -1e30f, l = 0.f;
    float o[32];
    for (int i = 0; i < 32; i++) o[i] = 0.f;

    int ntile = (qb + 1) * 2;  // keys 0 .. qb*64+63 in tiles of 32
    for (int kt = 0; kt < ntile; kt++) {
        int kbase = kt * 32;
        __syncthreads();  // prior iter's LDS reads done
        for (int i = 0; i < 16; i++) {
            int e = t * 16 + i;  // 32 keys x 128 dims
            int kk = e >> 7, dd = e & 127;
            size_t kr = (size_t)(b * 2048 + kbase + kk) * 6144 + h * 128 + dd;
            Ks[kk][dd] = qkv[kr + 2048];
            Vs[kk][dd] = qkv[kr + 4096];
        }
        __syncthreads();

        float s[32];
        for (int kk = 0; kk < 32; kk++) {
            float acc = 0.f;
            for (int i = 0; i < 32; i++) acc += qv[i] * Ks[kk][dseg * 32 + i];
            acc += __shfl_xor(acc, 1, 64);
            acc += __shfl_xor(acc, 2, 64);
            int key = kbase + kk;
            s[kk] = (key <= q) ? acc * scale : -1e30f;
        }
        float rmax = -1e30f;
        for (int kk = 0; kk < 32; kk++) rmax = fmaxf(rmax, s[kk]);
        float mnew = fmaxf(m, rmax);
        float alpha = __expf(m - mnew);
        m = mnew;
        float rsum = 0.f;
        for (int kk = 0; kk < 32; kk++) {
            s[kk] = __expf(s[kk] - mnew);
            rsum += s[kk];
        }
        l = l * alpha + rsum;
        for (int i = 0; i < 32; i++) o[i] *= alpha;
        for (int kk = 0; kk < 32; kk++) {
            float p = s[kk];
            for (int i = 0; i < 32; i++) o[i] += p * Vs[kk][dseg * 32 + i];
        }
    }

    float inv = 1.f / l;
    size_t outbase = (size_t)(b * 2048 + q) * 2048 + h * 128 + dseg * 32;
    for (int i = 0; i < 32; i++) out[outbase + i] = o[i] * inv;
}

extern "C" void kernel_launch(void* const* d_in, const int* in_sizes, int n_in,
                              void* d_out, int out_size, void* d_ws, size_t ws_size,
                              hipStream_t stream) {
    const float* x = nullptr;      // 2*2048*2048 = 8388608
    const float* Wqkv = nullptr;   // 2048*6144  = 12582912
    const float* Wo = nullptr;     // 2048*2048  = 4194304
    const float* freqs = nullptr;  // 2048*64*2  = 262144
    for (int i = 0; i < n_in; i++) {
        switch (in_sizes[i]) {
            case 8388608:  x = (const float*)d_in[i]; break;
            case 12582912: Wqkv = (const float*)d_in[i]; break;
            case 4194304:  Wo = (const float*)d_in[i]; break;
            case 262144:   freqs = (const float*)d_in[i]; break;
        }
    }
    if (!x) x = (const float*)d_in[0];
    if (!Wqkv) Wqkv = (const float*)d_in[1];
    if (!Wo) Wo = (const float*)d_in[2];
    if (!freqs) freqs = (const float*)d_in[3];

    float* out = (float*)d_out;  // [4096][2048] fp32
    char* ws = (char*)d_ws;

    // Workspace schedule (peak 128 MiB == previous kernel's proven footprint):
    //  [0, 96MiB)           qkv fp32 (live GEMM1 -> attn)
    //  [96MiB, +25.2MB)     WqkvT hi/lo half (live per GEMM1 half only)
    //  [96MiB, 128MiB)      attn fp32 (live attn -> GEMM2; WT region dead then)
    //  [0, 16.8MB)          WoT hi/lo (written after attn; qkv dead then)
    float* qkv = (float*)ws;                                  // 100663296 B
    u16* WTh = (u16*)(ws + 100663296);                        // 12582912 B
    u16* WTl = (u16*)(ws + 100663296 + 12582912);             // 12582912 B
    float* attnb = (float*)(ws + 100663296);                  // 33554432 B
    u16* WoTh = (u16*)ws;                                     // 8388608 B
    u16* WoTl = (u16*)(ws + 8388608);                         // 8388608 B

    // GEMM1 in two 3072-col halves: qkv = x @ Wqkv
    transpose_split<<<64 * 96, 256, 0, stream>>>(Wqkv, WTh, WTl, 2048, 6144, 0, 3072);
    gemm_split_bf16<<<32 * 24, 256, 0, stream>>>(x, WTh, WTl, qkv, 4096, 2048, 6144, 0, 3072);
    transpose_split<<<64 * 96, 256, 0, stream>>>(Wqkv, WTh, WTl, 2048, 6144, 3072, 3072);
    gemm_split_bf16<<<32 * 24, 256, 0, stream>>>(x, WTh, WTl, qkv, 4096, 2048, 6144, 3072, 3072);
    // RoPE on q,k halves
    rope_f32_v8<<<(4096 * 2048) / 256, 256, 0, stream>>>(qkv, freqs);
    // causal SDPA -> attn [4096][2048]
    attn_f32_v8<<<2 * 16 * 32, 256, 0, stream>>>(qkv, attnb);
    // out = attn @ Wo  (WoT transpose runs after attn: reuses dead qkv region)
    transpose_split<<<64 * 64, 256, 0, stream>>>(Wo, WoTh, WoTl, 2048, 2048, 0, 2048);
    gemm_split_bf16<<<32 * 16, 256, 0, stream>>>(attnb, WoTh, WoTl, out, 4096, 2048, 2048, 0, 2048);
}

// Round 2
// 833.166 us; speedup vs baseline: 10.5624x; 3.6309x over previous
//
#include <hip/hip_runtime.h>
#include <stdint.h>
#include <type_traits>

typedef unsigned short u16;
typedef __attribute__((ext_vector_type(8))) short short8_t;
typedef __attribute__((ext_vector_type(8))) __bf16 bf16x8_t;
typedef __attribute__((ext_vector_type(8))) unsigned short ushort8_t;
typedef __attribute__((ext_vector_type(4))) float f32x4;

// ROCm builds differ on the gfx950 bf16 MFMA builtin operand type
// (v8i16 vs v8bf16). Probe at compile time; bits are identical either way.
template <class T, class = void>
struct mfma_takes : std::false_type {};
template <class T>
struct mfma_takes<T, std::void_t<decltype(__builtin_amdgcn_mfma_f32_16x16x32_bf16(
                         std::declval<T>(), std::declval<T>(), std::declval<f32x4>(), 0, 0, 0))>>
    : std::true_type {};
using frag_t = std::conditional_t<mfma_takes<short8_t>::value, short8_t, bf16x8_t>;

__device__ __forceinline__ u16 bf16_rne(float f) {
    uint32_t u = __builtin_bit_cast(uint32_t, f);
    return (u16)((u + 0x7fffu + ((u >> 16) & 1u)) >> 16);
}
__device__ __forceinline__ float bf16_hi_f(u16 h) {
    return __builtin_bit_cast(float, (uint32_t)h << 16);
}
__device__ __forceinline__ frag_t pack_hi(float4 a, float4 b) {
    ushort8_t u;
    u[0] = bf16_rne(a.x); u[1] = bf16_rne(a.y); u[2] = bf16_rne(a.z); u[3] = bf16_rne(a.w);
    u[4] = bf16_rne(b.x); u[5] = bf16_rne(b.y); u[6] = bf16_rne(b.z); u[7] = bf16_rne(b.w);
    return __builtin_bit_cast(frag_t, u);
}
__device__ __forceinline__ frag_t pack_lo(float4 a, float4 b, frag_t hi) {
    ushort8_t uh = __builtin_bit_cast(ushort8_t, hi);
    ushort8_t u;
    u[0] = bf16_rne(a.x - bf16_hi_f(uh[0])); u[1] = bf16_rne(a.y - bf16_hi_f(uh[1]));
    u[2] = bf16_rne(a.z - bf16_hi_f(uh[2])); u[3] = bf16_rne(a.w - bf16_hi_f(uh[3]));
    u[4] = bf16_rne(b.x - bf16_hi_f(uh[4])); u[5] = bf16_rne(b.y - bf16_hi_f(uh[5]));
    u[6] = bf16_rne(b.z - bf16_hi_f(uh[6])); u[7] = bf16_rne(b.w - bf16_hi_f(uh[7]));
    return __builtin_bit_cast(frag_t, u);
}

// ---------- transpose + split fp32 W[K][Nfull] cols [c0,c0+Ncols) -> bf16 hi/lo [Ncols][K]
__global__ __launch_bounds__(256) void transpose_split(const float* __restrict__ W,
                                                       u16* __restrict__ Th,
                                                       u16* __restrict__ Tl,
                                                       int K, int Nfull, int c0, int Ncols) {
    __shared__ float tile[32][33];
    const int nb = Ncols >> 5;
    const int bk = blockIdx.x / nb;
    const int bn = blockIdx.x % nb;
    const int tx = threadIdx.x & 31;
    const int ty = threadIdx.x >> 5;
#pragma unroll
    for (int i = 0; i < 4; i++) {
        int r = (i << 3) + ty;
        tile[r][tx] = W[(size_t)((bk << 5) + r) * Nfull + c0 + (bn << 5) + tx];
    }
    __syncthreads();
#pragma unroll
    for (int i = 0; i < 4; i++) {
        int r = (i << 3) + ty;
        float v = tile[tx][r];
        u16 h = bf16_rne(v);
        u16 l = bf16_rne(v - bf16_hi_f(h));
        size_t o = (size_t)((bn << 5) + r) * K + (bk << 5) + tx;
        Th[o] = h;
        Tl[o] = l;
    }
}

// ---------- split-bf16 MFMA GEMM (unchanged, verified round 1) ----------
__global__ __launch_bounds__(256) void gemm_split_bf16(const float* __restrict__ A,
                                                       const u16* __restrict__ BTh,
                                                       const u16* __restrict__ BTl,
                                                       float* __restrict__ C,
                                                       int M, int K, int Nfull, int n0, int Nloc) {
    __shared__ alignas(16) u16 Ah[128][40];
    __shared__ alignas(16) u16 Al[128][40];
    __shared__ alignas(16) u16 Bh[128][40];
    __shared__ alignas(16) u16 Bl[128][40];

    const int t = threadIdx.x;
    const int nb = Nloc >> 7;
    const int bm = blockIdx.x / nb;
    const int bn = blockIdx.x % nb;
    const int m0 = bm << 7;
    const int nl0 = bn << 7;

    const int lane = t & 63;
    const int wid = t >> 6;
    const int wm = (wid >> 1) << 6;
    const int wn = (wid & 1) << 6;
    const int fr = lane & 15;
    const int fk = (lane >> 4) << 3;

    const int sr = t >> 3;
    const int sc = (t & 7) << 2;

    f32x4 acc[4][4];
#pragma unroll
    for (int m = 0; m < 4; m++)
#pragma unroll
        for (int n = 0; n < 4; n++) acc[m][n] = (f32x4)(0.0f);

    const int ksteps = K >> 5;
    for (int kt = 0; kt < ksteps; kt++) {
        const int k0 = kt << 5;
        if (kt) __syncthreads();
#pragma unroll
        for (int rg = 0; rg < 4; rg++) {
            int row = (rg << 5) + sr;
            float4 v = *(const float4*)(A + (size_t)(m0 + row) * K + k0 + sc);
            u16 hx = bf16_rne(v.x), hy = bf16_rne(v.y), hz = bf16_rne(v.z), hw = bf16_rne(v.w);
            *(ushort4*)&Ah[row][sc] = make_ushort4(hx, hy, hz, hw);
            *(ushort4*)&Al[row][sc] =
                make_ushort4(bf16_rne(v.x - bf16_hi_f(hx)), bf16_rne(v.y - bf16_hi_f(hy)),
                             bf16_rne(v.z - bf16_hi_f(hz)), bf16_rne(v.w - bf16_hi_f(hw)));
        }
#pragma unroll
        for (int rg = 0; rg < 4; rg++) {
            int row = (rg << 5) + sr;
            size_t o = (size_t)(nl0 + row) * K + k0 + sc;
            *(ushort4*)&Bh[row][sc] = *(const ushort4*)(BTh + o);
            *(ushort4*)&Bl[row][sc] = *(const ushort4*)(BTl + o);
        }
        __syncthreads();

        frag_t ah[4], al[4], bh[4], bl[4];
#pragma unroll
        for (int i = 0; i < 4; i++) {
            int r = (i << 4) + fr;
            ah[i] = *(const frag_t*)&Ah[wm + r][fk];
            al[i] = *(const frag_t*)&Al[wm + r][fk];
            bh[i] = *(const frag_t*)&Bh[wn + r][fk];
            bl[i] = *(const frag_t*)&Bl[wn + r][fk];
        }
#pragma unroll
        for (int m = 0; m < 4; m++)
#pragma unroll
            for (int n = 0; n < 4; n++) {
                acc[m][n] = __builtin_amdgcn_mfma_f32_16x16x32_bf16(ah[m], bh[n], acc[m][n], 0, 0, 0);
                acc[m][n] = __builtin_amdgcn_mfma_f32_16x16x32_bf16(al[m], bh[n], acc[m][n], 0, 0, 0);
                acc[m][n] = __builtin_amdgcn_mfma_f32_16x16x32_bf16(ah[m], bl[n], acc[m][n], 0, 0, 0);
            }
    }

#pragma unroll
    for (int m = 0; m < 4; m++) {
        int r0 = m0 + wm + (m << 4) + ((lane >> 4) << 2);
#pragma unroll
        for (int n = 0; n < 4; n++) {
            int cc = n0 + nl0 + wn + (n << 4) + fr;
#pragma unroll
            for (int r = 0; r < 4; r++)
                C[(size_t)(r0 + r) * Nfull + cc] = acc[m][n][r];
        }
    }
}

// ---------- RoPE fp32 in-place on q,k halves of qkv [4096][6144] (unchanged) ----------
__global__ __launch_bounds__(256) void rope_f32_v8(float* __restrict__ qkv,
                                                   const float* __restrict__ freqs) {
    int idx = blockIdx.x * 256 + threadIdx.x;
    int row = idx >> 11;
    int p = idx & 2047;
    int part = p >> 10;
    int rem = p & 1023;
    int h = rem >> 6;
    int d2 = rem & 63;
    int s = row & 2047;
    size_t base = (size_t)row * 6144 + part * 2048 + h * 128 + 2 * d2;
    float c = freqs[(s * 64 + d2) * 2 + 0];
    float sn = freqs[(s * 64 + d2) * 2 + 1];
    float x0 = qkv[base];
    float x1 = qkv[base + 1];
    qkv[base] = x0 * c - x1 * sn;
    qkv[base + 1] = x1 * c + x0 * sn;
}

// ---------- MFMA causal flash attention ----------
// Block = (b, h, 128 q-rows). 4 waves x 32 q-rows each; KV tile = 64 keys.
// QK^T: split-bf16 3-MFMA (fp32-accurate scores). Softmax: shfl over fr-lanes.
// PV: P (plain bf16) via per-wave LDS round trip; V staged transposed (plain
// bf16) with 16B-block XOR swizzle for aligned ds_read_b128.
__global__ __launch_bounds__(256, 2) void attn_mfma(const float* __restrict__ qkv,
                                                    float* __restrict__ out) {
    __shared__ alignas(16) u16 Kh[64][136];
    __shared__ alignas(16) u16 Kl[64][136];
    __shared__ alignas(16) u16 Vt[128][72];   // [d][swizzled key]
    __shared__ alignas(16) u16 Plds[4][32][72];

    const int t = threadIdx.x;
    const int lane = t & 63;
    const int w = t >> 6;
    const int g = lane >> 4;   // 0..3
    const int fr = lane & 15;  // 0..15

    const int bid = blockIdx.x;
    const int bh = bid & 31;
    const int x = bid >> 5;
    const int qb = (x & 1) ? (15 - (x >> 1)) : (x >> 1);  // light/heavy interleave
    const int b = bh >> 4;
    const int h = bh & 15;
    const int q0b = qb << 7;
    const int q0w = q0b + (w << 5);
    const float scale = 0.08838834764831845f;  // 1/sqrt(128)

    // ---- load Q fragments (hi/lo split), RoPE'd in place already ----
    frag_t qh[2][4], ql[2][4];
#pragma unroll
    for (int m = 0; m < 2; m++) {
        const float* qp = qkv + (size_t)(b * 2048 + q0w + m * 16 + fr) * 6144 + h * 128 + g * 8;
#pragma unroll
        for (int ks = 0; ks < 4; ks++) {
            float4 v0 = *(const float4*)(qp + ks * 32);
            float4 v1 = *(const float4*)(qp + ks * 32 + 4);
            qh[m][ks] = pack_hi(v0, v1);
            ql[m][ks] = pack_lo(v0, v1, qh[m][ks]);
        }
    }

    f32x4 o[2][8];
#pragma unroll
    for (int m = 0; m < 2; m++)
#pragma unroll
        for (int n = 0; n < 8; n++) o[m][n] = (f32x4)(0.0f);
    float m_i[2][4], l_i[2][4];
#pragma unroll
    for (int m = 0; m < 2; m++)
#pragma unroll
        for (int r = 0; r < 4; r++) { m_i[m][r] = -1e30f; l_i[m][r] = 0.f; }

    // staging index precompute
    const int kr = t >> 3;          // 0..31 (K rows, 2 passes)
    const int kc = (t & 7) << 4;    // 0..112
    const int vr = t >> 2;          // 0..63 (V rows)
    const int vc = (t & 3) << 5;    // 0,32,64,96

    const int ntile = 2 * qb + 2;
    for (int kt = 0; kt < ntile; kt++) {
        const int kbase = kt << 6;
        if (kt) __syncthreads();

        // ---- stage K (hi/lo split) ----
        {
            const float* ksrc = qkv + (size_t)(b * 2048 + kbase) * 6144 + 2048 + h * 128;
#pragma unroll
            for (int p = 0; p < 2; p++) {
                int row = kr + (p << 5);
                const float* src = ksrc + (size_t)row * 6144 + kc;
#pragma unroll
                for (int i = 0; i < 4; i++) {
                    float4 v = *(const float4*)(src + (i << 2));
                    u16 h0 = bf16_rne(v.x), h1 = bf16_rne(v.y), h2 = bf16_rne(v.z), h3 = bf16_rne(v.w);
                    *(ushort4*)&Kh[row][kc + (i << 2)] = make_ushort4(h0, h1, h2, h3);
                    *(ushort4*)&Kl[row][kc + (i << 2)] = make_ushort4(
                        bf16_rne(v.x - bf16_hi_f(h0)), bf16_rne(v.y - bf16_hi_f(h1)),
                        bf16_rne(v.z - bf16_hi_f(h2)), bf16_rne(v.w - bf16_hi_f(h3)));
                }
            }
        }
        // ---- stage V transposed (plain bf16), 16B-block swizzle ----
        {
            const float* vsrc = qkv + (size_t)(b * 2048 + kbase + vr) * 6144 + 4096 + h * 128 + vc;
#pragma unroll
            for (int i = 0; i < 8; i++) {
                float4 v = *(const float4*)(vsrc + (i << 2));
                int d0 = vc + (i << 2);
#pragma unroll
                for (int j = 0; j < 4; j++) {
                    int d = d0 + j;
                    float f = j == 0 ? v.x : (j == 1 ? v.y : (j == 2 ? v.z : v.w));
                    int sw = (vr & 7) + ((((vr >> 3) ^ ((d >> 5) & 3))) << 3);
                    Vt[d][sw] = bf16_rne(f);
                }
            }
        }
        __syncthreads();

        if (kbase > q0w + 31) continue;  // fully masked for this wave (barriers stay uniform)

        // ---- QK^T: S[32 q][64 key], split-bf16 3-MFMA ----
        f32x4 s[2][4];
#pragma unroll
        for (int m = 0; m < 2; m++)
#pragma unroll
            for (int n = 0; n < 4; n++) s[m][n] = (f32x4)(0.0f);
#pragma unroll
        for (int ks = 0; ks < 4; ks++) {
            frag_t kh[4], kl[4];
#pragma unroll
            for (int n = 0; n < 4; n++) {
                kh[n] = *(const frag_t*)&Kh[n * 16 + fr][ks * 32 + g * 8];
                kl[n] = *(const frag_t*)&Kl[n * 16 + fr][ks * 32 + g * 8];
            }
#pragma unroll
            for (int m = 0; m < 2; m++)
#pragma unroll
                for (int n = 0; n < 4; n++) {
                    s[m][n] = __builtin_amdgcn_mfma_f32_16x16x32_bf16(qh[m][ks], kh[n], s[m][n], 0, 0, 0);
                    s[m][n] = __builtin_amdgcn_mfma_f32_16x16x32_bf16(ql[m][ks], kh[n], s[m][n], 0, 0, 0);
                    s[m][n] = __builtin_amdgcn_mfma_f32_16x16x32_bf16(qh[m][ks], kl[n], s[m][n], 0, 0, 0);
                }
        }

        // ---- scale + causal mask ----
        const bool needmask = (kbase + 63 > q0w);
#pragma unroll
        for (int m = 0; m < 2; m++)
#pragma unroll
            for (int n = 0; n < 4; n++)
#pragma unroll
                for (int r = 0; r < 4; r++) {
                    float sv = s[m][n][r] * scale;
                    if (needmask) {
                        int key = kbase + n * 16 + fr;
                        int qg = q0w + m * 16 + (g << 2) + r;
                        if (key > qg) sv = -1e30f;
                    }
                    s[m][n][r] = sv;
                }

        // ---- online softmax (per lane-row: 8 rows, keys across n regs + fr lanes) ----
        float alpha_[2][4];
#pragma unroll
        for (int m = 0; m < 2; m++)
#pragma unroll
            for (int r = 0; r < 4; r++) {
                float v = fmaxf(fmaxf(s[m][0][r], s[m][1][r]), fmaxf(s[m][2][r], s[m][3][r]));
                v = fmaxf(v, __shfl_xor(v, 1, 64));
                v = fmaxf(v, __shfl_xor(v, 2, 64));
                v = fmaxf(v, __shfl_xor(v, 4, 64));
                v = fmaxf(v, __shfl_xor(v, 8, 64));
                float mn = fmaxf(m_i[m][r], v);
                alpha_[m][r] = __expf(m_i[m][r] - mn);
                m_i[m][r] = mn;
            }
#pragma unroll
        for (int m = 0; m < 2; m++)
#pragma unroll
            for (int r = 0; r < 4; r++) {
                float rs = 0.f;
#pragma unroll
                for (int n = 0; n < 4; n++) {
                    float p = __expf(s[m][n][r] - m_i[m][r]);
                    s[m][n][r] = p;
                    rs += p;
                }
                rs += __shfl_xor(rs, 1, 64);
                rs += __shfl_xor(rs, 2, 64);
                rs += __shfl_xor(rs, 4, 64);
                rs += __shfl_xor(rs, 8, 64);
                l_i[m][r] = l_i[m][r] * alpha_[m][r] + rs;
            }

        // ---- P -> per-wave LDS (C/D layout -> A-frag layout round trip) ----
#pragma unroll
        for (int m = 0; m < 2; m++)
#pragma unroll
            for (int n = 0; n < 4; n++)
#pragma unroll
                for (int r = 0; r < 4; r++)
                    Plds[w][m * 16 + (g << 2) + r][n * 16 + fr] = bf16_rne(s[m][n][r]);

        // ---- rescale O ----
#pragma unroll
        for (int m = 0; m < 2; m++)
#pragma unroll
            for (int n = 0; n < 8; n++)
#pragma unroll
                for (int r = 0; r < 4; r++) o[m][n][r] *= alpha_[m][r];

        // ---- PV: O[32 q][128 d] += P[32][64] @ V[64][128] ----
#pragma unroll
        for (int ks = 0; ks < 2; ks++) {
            frag_t pa[2];
#pragma unroll
            for (int m = 0; m < 2; m++)
                pa[m] = *(const frag_t*)&Plds[w][m * 16 + fr][ks * 32 + g * 8];
#pragma unroll
            for (int n = 0; n < 8; n++) {
                frag_t vb = *(const frag_t*)&Vt[n * 16 + fr][((4 * ks + g) ^ ((n >> 1) & 3)) << 3];
                o[0][n] = __builtin_amdgcn_mfma_f32_16x16x32_bf16(pa[0], vb, o[0][n], 0, 0, 0);
                o[1][n] = __builtin_amdgcn_mfma_f32_16x16x32_bf16(pa[1], vb, o[1][n], 0, 0, 0);
            }
        }
    }

    // ---- epilogue ----
#pragma unroll
    for (int m = 0; m < 2; m++)
#pragma unroll
        for (int r = 0; r < 4; r++) {
            float inv = 1.f / l_i[m][r];
            size_t rowoff = (size_t)(b * 2048 + q0w + m * 16 + (g << 2) + r) * 2048 + h * 128;
#pragma unroll
            for (int n = 0; n < 8; n++)
                out[rowoff + n * 16 + fr] = o[m][n][r] * inv;
        }
}

extern "C" void kernel_launch(void* const* d_in, const int* in_sizes, int n_in,
                              void* d_out, int out_size, void* d_ws, size_t ws_size,
                              hipStream_t stream) {
    const float* x = nullptr;
    const float* Wqkv = nullptr;
    const float* Wo = nullptr;
    const float* freqs = nullptr;
    for (int i = 0; i < n_in; i++) {
        switch (in_sizes[i]) {
            case 8388608:  x = (const float*)d_in[i]; break;
            case 12582912: Wqkv = (const float*)d_in[i]; break;
            case 4194304:  Wo = (const float*)d_in[i]; break;
            case 262144:   freqs = (const float*)d_in[i]; break;
        }
    }
    if (!x) x = (const float*)d_in[0];
    if (!Wqkv) Wqkv = (const float*)d_in[1];
    if (!Wo) Wo = (const float*)d_in[2];
    if (!freqs) freqs = (const float*)d_in[3];

    float* out = (float*)d_out;
    char* ws = (char*)d_ws;

    // Workspace schedule (peak 128 MiB, proven):
    //  [0, 96MiB)           qkv fp32 (live GEMM1 -> attn)
    //  [96MiB, +25.2MB)     WqkvT hi/lo half (live per GEMM1 half only)
    //  [96MiB, 128MiB)      attn fp32 (live attn -> GEMM2)
    //  [0, 16.8MB)          WoT hi/lo (written after attn; qkv dead then)
    float* qkv = (float*)ws;
    u16* WTh = (u16*)(ws + 100663296);
    u16* WTl = (u16*)(ws + 100663296 + 12582912);
    float* attnb = (float*)(ws + 100663296);
    u16* WoTh = (u16*)ws;
    u16* WoTl = (u16*)(ws + 8388608);

    // GEMM1 in two 3072-col halves: qkv = x @ Wqkv
    transpose_split<<<64 * 96, 256, 0, stream>>>(Wqkv, WTh, WTl, 2048, 6144, 0, 3072);
    gemm_split_bf16<<<32 * 24, 256, 0, stream>>>(x, WTh, WTl, qkv, 4096, 2048, 6144, 0, 3072);
    transpose_split<<<64 * 96, 256, 0, stream>>>(Wqkv, WTh, WTl, 2048, 6144, 3072, 3072);
    gemm_split_bf16<<<32 * 24, 256, 0, stream>>>(x, WTh, WTl, qkv, 4096, 2048, 6144, 3072, 3072);
    // RoPE on q,k halves
    rope_f32_v8<<<(4096 * 2048) / 256, 256, 0, stream>>>(qkv, freqs);
    // causal SDPA (MFMA flash) -> attn [4096][2048]
    attn_mfma<<<512, 256, 0, stream>>>(qkv, attnb);
    // out = attn @ Wo
    transpose_split<<<64 * 64, 256, 0, stream>>>(Wo, WoTh, WoTl, 2048, 2048, 0, 2048);
    gemm_split_bf16<<<32 * 16, 256, 0, stream>>>(attnb, WoTh, WoTl, out, 4096, 2048, 2048, 0, 2048);
}